// Round 1
// baseline (791.147 us; speedup 1.0000x reference)
//
#include <hip/hip_runtime.h>
#include <math.h>

#define NN 50000
#define NE 800000
#define NB 1024
// F_IN=128, HID=128, EMB=64, NREL=3, NBASES=2

// ---------------------------------------------------------------------------
// Build stacked weights:
//   W1stack [512,128] = vstack(root1, W1[0], W1[1], W1[2]),  W1[r]=sum_b comp1[r,b]*basis1[b]
//   W2stack [512, 64] = vstack(root2, W2[0], W2[1], W2[2])
// ---------------------------------------------------------------------------
__global__ void build_w_kernel(const float* __restrict__ basis1, const float* __restrict__ comp1,
                               const float* __restrict__ root1,
                               const float* __restrict__ basis2, const float* __restrict__ comp2,
                               const float* __restrict__ root2,
                               float* __restrict__ W1, float* __restrict__ W2)
{
    int idx = blockIdx.x * 256 + threadIdx.x;
    if (idx < 512 * 128) {
        int k = idx >> 7, j = idx & 127;
        float v;
        if (k < 128) {
            v = root1[k * 128 + j];
        } else {
            int r = (k - 128) >> 7;
            int i = (k - 128) & 127;
            v = comp1[r * 2 + 0] * basis1[0 * 128 * 128 + i * 128 + j]
              + comp1[r * 2 + 1] * basis1[1 * 128 * 128 + i * 128 + j];
        }
        W1[idx] = v;
    } else {
        int t = idx - 512 * 128;
        if (t < 512 * 64) {
            int k = t >> 6, j = t & 63;
            float v;
            if (k < 128) {
                v = root2[k * 64 + j];
            } else {
                int r = (k - 128) >> 7;
                int i = (k - 128) & 127;
                v = comp2[r * 2 + 0] * basis2[0 * 128 * 64 + i * 64 + j]
                  + comp2[r * 2 + 1] * basis2[1 * 128 * 64 + i * 64 + j];
            }
            W2[t] = v;
        }
    }
}

// ---------------------------------------------------------------------------
// CSR build: in-degree histogram + per-relation counts
// ---------------------------------------------------------------------------
__global__ void hist_kernel(const int* __restrict__ ei, const int* __restrict__ et,
                            int* __restrict__ deg, int* __restrict__ cnt)
{
    for (int e = blockIdx.x * blockDim.x + threadIdx.x; e < NE; e += gridDim.x * blockDim.x) {
        int dst = ei[NE + e];
        int t   = et[e];
        atomicAdd(&deg[dst], 1);
        atomicAdd(&cnt[t * NN + dst], 1);
    }
}

// Exclusive scan of deg[NN] -> offs[NN+1], single block of 1024 threads
__global__ void scan_kernel(const int* __restrict__ deg, int* __restrict__ offs)
{
    __shared__ int sums[1024];
    int tid = threadIdx.x;
    const int per = (NN + 1023) / 1024;  // 49
    int base = tid * per;
    int s = 0;
    for (int i = 0; i < per; i++) {
        int idx = base + i;
        if (idx < NN) s += deg[idx];
    }
    sums[tid] = s;
    __syncthreads();
    for (int o = 1; o < 1024; o <<= 1) {
        int t = (tid >= o) ? sums[tid - o] : 0;
        __syncthreads();
        sums[tid] += t;
        __syncthreads();
    }
    int run = sums[tid] - s;  // exclusive prefix
    for (int i = 0; i < per; i++) {
        int idx = base + i;
        if (idx < NN) { offs[idx] = run; run += deg[idx]; }
    }
    if (tid == 1023) offs[NN] = run;
}

// Scatter packed edges into CSR slots: ep[slot] = src | (type<<16)  (src<65536, type<4)
__global__ void scatter_kernel(const int* __restrict__ ei, const int* __restrict__ et,
                               const int* __restrict__ offs, int* __restrict__ cursor,
                               unsigned* __restrict__ ep)
{
    for (int e = blockIdx.x * blockDim.x + threadIdx.x; e < NE; e += gridDim.x * blockDim.x) {
        int src = ei[e];
        int dst = ei[NE + e];
        int t   = et[e];
        int pos = offs[dst] + atomicAdd(&cursor[dst], 1);
        ep[pos] = (unsigned)src | ((unsigned)t << 16);
    }
}

// ---------------------------------------------------------------------------
// Aggregation: one warp per destination node; gathers raw X rows (128 floats,
// float2 per lane), accumulates per-relation sums, divides by counts.
// Writes Sbar [NN, 384]: cols r*128.. for relation r.
// ---------------------------------------------------------------------------
__global__ __launch_bounds__(256)
void agg_kernel(const float* __restrict__ X, int ldx,
                const unsigned* __restrict__ ep, const int* __restrict__ offs,
                const int* __restrict__ cnt,
                float* __restrict__ out)
{
    int gid  = blockIdx.x * 256 + threadIdx.x;
    int node = gid >> 6;
    int lane = threadIdx.x & 63;
    if (node >= NN) return;
    int beg = offs[node], end = offs[node + 1];
    float a0x = 0.f, a0y = 0.f, a1x = 0.f, a1y = 0.f, a2x = 0.f, a2y = 0.f;
    const float* Xl = X + lane * 2;
    for (int i = beg; i < end; i++) {
        unsigned p = ep[i];                 // wave-uniform
        int src    = (int)(p & 0xFFFFu);
        unsigned t = p >> 16;               // wave-uniform -> no divergence
        float2 v = *(const float2*)(Xl + (size_t)src * ldx);
        if (t == 0)      { a0x += v.x; a0y += v.y; }
        else if (t == 1) { a1x += v.x; a1y += v.y; }
        else             { a2x += v.x; a2y += v.y; }
    }
    float s0 = 1.f / fmaxf((float)cnt[node], 1.f);
    float s1 = 1.f / fmaxf((float)cnt[NN + node], 1.f);
    float s2 = 1.f / fmaxf((float)cnt[2 * NN + node], 1.f);
    float* o = out + (size_t)node * 384 + lane * 2;
    *(float2*)(o)       = make_float2(a0x * s0, a0y * s0);
    *(float2*)(o + 128) = make_float2(a1x * s1, a1y * s1);
    *(float2*)(o + 256) = make_float2(a2x * s2, a2y * s2);
}

// ---------------------------------------------------------------------------
// Fused GEMM: C[N,BN] = [Aa | Ab] [N,512] @ W[512,BN] + bias (, relu)
// Aa = raw features [N,128]; Ab = Sbar [N,384].
// Block: 128 rows x BN cols, BK=32, 256 threads, per-thread 8 x (BN/16).
// ---------------------------------------------------------------------------
template<int BN, bool RELU>
__global__ __launch_bounds__(256)
void gemm_kernel(const float* __restrict__ Aa,
                 const float* __restrict__ Ab,
                 const float* __restrict__ W,
                 const float* __restrict__ bias,
                 float* __restrict__ C, int ldc, int nrows)
{
    constexpr int TN = BN / 16;
    __shared__ float As[128][33];
    __shared__ float Ws[32][BN + 1];
    int tid  = threadIdx.x;
    int row0 = blockIdx.x * 128;
    int tr = tid >> 4, tc = tid & 15;
    float acc[8][TN];
#pragma unroll
    for (int i = 0; i < 8; i++)
#pragma unroll
        for (int j = 0; j < TN; j++) acc[i][j] = 0.f;

    int ar = tid >> 3;          // 0..31
    int ac = (tid & 7) * 4;     // 0..28

    for (int k0 = 0; k0 < 512; k0 += 32) {
        const float* Asrc;
        int lda, cbase;
        if (k0 < 128) { Asrc = Aa; lda = 128; cbase = k0; }
        else          { Asrc = Ab; lda = 384; cbase = k0 - 128; }
#pragma unroll
        for (int jj = 0; jj < 4; jj++) {
            int r  = ar + jj * 32;
            int rr = row0 + r;
            if (rr > nrows - 1) rr = nrows - 1;   // clamp (safe read)
            float4 v = *(const float4*)(Asrc + (size_t)rr * lda + cbase + ac);
            As[r][ac]     = v.x;
            As[r][ac + 1] = v.y;
            As[r][ac + 2] = v.z;
            As[r][ac + 3] = v.w;
        }
#pragma unroll
        for (int jj = 0; jj < BN / 32; jj++) {
            int f  = tid + 256 * jj;
            int wr = f / (BN / 4);
            int wc = (f % (BN / 4)) * 4;
            float4 v = *(const float4*)(W + (size_t)(k0 + wr) * BN + wc);
            Ws[wr][wc]     = v.x;
            Ws[wr][wc + 1] = v.y;
            Ws[wr][wc + 2] = v.z;
            Ws[wr][wc + 3] = v.w;
        }
        __syncthreads();
#pragma unroll
        for (int kk = 0; kk < 32; kk++) {
            float a[8], b[TN];
#pragma unroll
            for (int i = 0; i < 8; i++) a[i] = As[tr + i * 16][kk];
#pragma unroll
            for (int j = 0; j < TN; j++) b[j] = Ws[kk][tc + j * 16];
#pragma unroll
            for (int i = 0; i < 8; i++)
#pragma unroll
                for (int j = 0; j < TN; j++)
                    acc[i][j] = fmaf(a[i], b[j], acc[i][j]);
        }
        __syncthreads();
    }

#pragma unroll
    for (int i = 0; i < 8; i++) {
        int r = row0 + tr + i * 16;
        if (r < nrows) {
#pragma unroll
            for (int j = 0; j < TN; j++) {
                int c = tc + j * 16;
                float v = acc[i][j] + bias[c];
                if (RELU) v = fmaxf(v, 0.f);
                C[(size_t)r * ldc + c] = v;
            }
        }
    }
}

// ---------------------------------------------------------------------------
// Final: pair = [emb[nest] | emb[food]] ; out = tanh(pair @ fc_w + fc_b)
// ---------------------------------------------------------------------------
__global__ __launch_bounds__(128)
void fc_kernel(const float* __restrict__ emb, const int* __restrict__ nest,
               const int* __restrict__ food, const float* __restrict__ fw,
               const float* __restrict__ fb, float* __restrict__ out)
{
    __shared__ float pr[128];
    int p = blockIdx.x, j = threadIdx.x;
    int n0 = nest[p], n1 = food[p];
    pr[j] = (j < 64) ? emb[(size_t)n0 * 64 + j] : emb[(size_t)n1 * 64 + (j - 64)];
    __syncthreads();
    float acc = fb[j];
#pragma unroll 8
    for (int k = 0; k < 128; k++) acc = fmaf(pr[k], fw[k * 128 + j], acc);
    out[(size_t)p * 128 + j] = tanhf(acc);
}

// ---------------------------------------------------------------------------
extern "C" void kernel_launch(void* const* d_in, const int* in_sizes, int n_in,
                              void* d_out, int out_size, void* d_ws, size_t ws_size,
                              hipStream_t stream)
{
    const float* x      = (const float*)d_in[0];
    const int*   ei     = (const int*)d_in[1];
    // d_in[2] = edge_attr : unused (binned distances are dead code in reference)
    const int*   et     = (const int*)d_in[3];
    const int*   nest   = (const int*)d_in[4];
    const int*   food   = (const int*)d_in[5];
    const float* basis1 = (const float*)d_in[6];
    const float* comp1  = (const float*)d_in[7];
    const float* root1  = (const float*)d_in[8];
    const float* bias1  = (const float*)d_in[9];
    const float* basis2 = (const float*)d_in[10];
    const float* comp2  = (const float*)d_in[11];
    const float* root2  = (const float*)d_in[12];
    const float* bias2  = (const float*)d_in[13];
    const float* fw     = (const float*)d_in[14];
    const float* fb     = (const float*)d_in[15];

    char* ws = (char*)d_ws;
    size_t off = 0;
    auto take = [&](size_t bytes) -> char* {
        char* p = ws + off;
        off += (bytes + 255) & ~(size_t)255;
        return p;
    };
    int*      deg    = (int*)take((size_t)NN * 4);
    int*      cursor = (int*)take((size_t)NN * 4);
    int*      cnt    = (int*)take((size_t)3 * NN * 4);
    size_t    zero_bytes = (size_t)((char*)(cnt + 3 * NN) - (char*)deg);
    int*      offs   = (int*)take((size_t)(NN + 1) * 4);
    unsigned* ep     = (unsigned*)take((size_t)NE * 4);
    float*    W1     = (float*)take((size_t)512 * 128 * 4);
    float*    W2     = (float*)take((size_t)512 * 64 * 4);
    float*    Sbar   = (float*)take((size_t)NN * 384 * 4);
    float*    h      = (float*)take((size_t)NN * 128 * 4);
    float*    emb    = (float*)take((size_t)NN * 64 * 4);

    hipMemsetAsync(deg, 0, zero_bytes, stream);

    build_w_kernel<<<384, 256, 0, stream>>>(basis1, comp1, root1, basis2, comp2, root2, W1, W2);
    hist_kernel<<<1024, 256, 0, stream>>>(ei, et, deg, cnt);
    scan_kernel<<<1, 1024, 0, stream>>>(deg, offs);
    scatter_kernel<<<1024, 256, 0, stream>>>(ei, et, offs, cursor, ep);

    // Layer 1: aggregate raw x, then fused GEMM (+bias1, relu) -> h [NN,128]
    agg_kernel<<<(NN * 64 + 255) / 256, 256, 0, stream>>>(x, 128, ep, offs, cnt, Sbar);
    gemm_kernel<128, true><<<(NN + 127) / 128, 256, 0, stream>>>(x, Sbar, W1, bias1, h, 128, NN);

    // Layer 2: aggregate h, fused GEMM (+bias2) -> emb [NN,64]
    agg_kernel<<<(NN * 64 + 255) / 256, 256, 0, stream>>>(h, 128, ep, offs, cnt, Sbar);
    gemm_kernel<64, false><<<(NN + 127) / 128, 256, 0, stream>>>(h, Sbar, W2, bias2, emb, 64, NN);

    // Pair MLP
    fc_kernel<<<NB, 128, 0, stream>>>(emb, nest, food, fw, fb, (float*)d_out);
}

// Round 2
// 565.012 us; speedup vs baseline: 1.4002x; 1.4002x over previous
//
#include <hip/hip_runtime.h>
#include <math.h>

#define NN 50000
#define NE 800000
#define NB 1024
// F_IN=128, HID=128, EMB=64, NREL=3, NBASES=2

typedef short short8 __attribute__((ext_vector_type(8)));
typedef float f32x4 __attribute__((ext_vector_type(4)));
typedef unsigned int u32;
typedef unsigned short u16;

__device__ __forceinline__ u16 f2bf(float f) {
    u32 u = __builtin_bit_cast(u32, f);
    u = (u + 0x7FFFu + ((u >> 16) & 1u)) >> 16;
    return (u16)u;
}
__device__ __forceinline__ float bf2f(u16 h) {
    u32 u = ((u32)h) << 16;
    return __builtin_bit_cast(float, u);
}

#define GL2LDS(gp, lp) __builtin_amdgcn_global_load_lds( \
    (const __attribute__((address_space(1))) void*)(gp), \
    (__attribute__((address_space(3))) void*)(lp), 16, 0, 0)

// ---------------------------------------------------------------------------
// Build stacked weights as TRANSPOSED bf16 hi/lo planes:
//   Wt1[n][k], n<128, k<512 : k<128 -> root1[k][n]; else W1[r][i][n]
//   Wt2[n][k], n<64
// ---------------------------------------------------------------------------
__global__ void build_w_kernel(const float* basis1, const float* comp1, const float* root1,
                               const float* basis2, const float* comp2, const float* root2,
                               u16* W1h, u16* W1l, u16* W2h, u16* W2l)
{
    int idx = blockIdx.x * 256 + threadIdx.x;   // 384*256 = 98304 exactly
    if (idx < 512 * 128) {
        int k = idx >> 7, j = idx & 127;
        float v;
        if (k < 128) v = root1[k * 128 + j];
        else {
            int r = (k - 128) >> 7, i = (k - 128) & 127;
            v = comp1[r * 2] * basis1[i * 128 + j]
              + comp1[r * 2 + 1] * basis1[128 * 128 + i * 128 + j];
        }
        u16 hi = f2bf(v); u16 lo = f2bf(v - bf2f(hi));
        W1h[j * 512 + k] = hi;
        W1l[j * 512 + k] = lo;
    } else {
        int t = idx - 512 * 128;                // < 512*64
        int k = t >> 6, j = t & 63;
        float v;
        if (k < 128) v = root2[k * 64 + j];
        else {
            int r = (k - 128) >> 7, i = (k - 128) & 127;
            v = comp2[r * 2] * basis2[i * 64 + j]
              + comp2[r * 2 + 1] * basis2[128 * 64 + i * 64 + j];
        }
        u16 hi = f2bf(v); u16 lo = f2bf(v - bf2f(hi));
        W2h[j * 512 + k] = hi;
        W2l[j * 512 + k] = lo;
    }
}

// Convert x [NN,128] fp32 -> A planes cols 0..127
__global__ __launch_bounds__(256)
void convert_x_kernel(const float* x, u16* Ahi, u16* Alo)
{
    int idx = blockIdx.x * 256 + threadIdx.x;   // NN*64
    if (idx >= NN * 64) return;
    int r = idx >> 6, c = (idx & 63) * 2;
    float2 v = *(const float2*)(x + (size_t)r * 128 + c);
    u16 hx = f2bf(v.x), hy = f2bf(v.y);
    u16 lx = f2bf(v.x - bf2f(hx)), ly = f2bf(v.y - bf2f(hy));
    size_t o = (size_t)r * 512 + c;
    *(u32*)(Ahi + o) = (u32)hx | ((u32)hy << 16);
    *(u32*)(Alo + o) = (u32)lx | ((u32)ly << 16);
}

// ---------------------------------------------------------------------------
// CSR build
// ---------------------------------------------------------------------------
__global__ void hist_kernel(const int* __restrict__ ei, const int* __restrict__ et,
                            int* __restrict__ deg, int* __restrict__ cnt)
{
    for (int e = blockIdx.x * blockDim.x + threadIdx.x; e < NE; e += gridDim.x * blockDim.x) {
        int dst = ei[NE + e];
        int t   = et[e];
        atomicAdd(&deg[dst], 1);
        atomicAdd(&cnt[t * NN + dst], 1);
    }
}

__global__ void scan_kernel(const int* __restrict__ deg, int* __restrict__ offs)
{
    __shared__ int sums[1024];
    int tid = threadIdx.x;
    const int per = (NN + 1023) / 1024;  // 49
    int base = tid * per;
    int s = 0;
    for (int i = 0; i < per; i++) {
        int idx = base + i;
        if (idx < NN) s += deg[idx];
    }
    sums[tid] = s;
    __syncthreads();
    for (int o = 1; o < 1024; o <<= 1) {
        int t = (tid >= o) ? sums[tid - o] : 0;
        __syncthreads();
        sums[tid] += t;
        __syncthreads();
    }
    int run = sums[tid] - s;
    for (int i = 0; i < per; i++) {
        int idx = base + i;
        if (idx < NN) { offs[idx] = run; run += deg[idx]; }
    }
    if (tid == 1023) offs[NN] = run;
}

__global__ void scatter_kernel(const int* __restrict__ ei, const int* __restrict__ et,
                               const int* __restrict__ offs, int* __restrict__ cursor,
                               unsigned* __restrict__ ep)
{
    for (int e = blockIdx.x * blockDim.x + threadIdx.x; e < NE; e += gridDim.x * blockDim.x) {
        int src = ei[e];
        int dst = ei[NE + e];
        int t   = et[e];
        int pos = offs[dst] + atomicAdd(&cursor[dst], 1);
        ep[pos] = (unsigned)src | ((unsigned)t << 16);
    }
}

// ---------------------------------------------------------------------------
// Aggregation: one wave per dst node. FROMX: gather fp32 x rows; else gather
// hi+lo bf16 planes cols 0..127 (exact-ish reconstruct). Writes per-relation
// means into A planes cols 128 + r*128 as hi/lo bf16.
// ---------------------------------------------------------------------------
template<bool FROMX>
__global__ __launch_bounds__(256)
void agg_kernel(const float* X, const u16* Hhi, const u16* Hlo,
                const unsigned* ep, const int* offs, const int* cnt,
                u16* Shi, u16* Slo)
{
    int gid  = blockIdx.x * 256 + threadIdx.x;
    int node = gid >> 6;
    int lane = threadIdx.x & 63;
    if (node >= NN) return;
    int beg = offs[node], end = offs[node + 1];
    float a0x = 0.f, a0y = 0.f, a1x = 0.f, a1y = 0.f, a2x = 0.f, a2y = 0.f;
    for (int i = beg; i < end; i++) {
        unsigned p = ep[i];                 // wave-uniform
        int src    = (int)(p & 0xFFFFu);
        unsigned t = p >> 16;               // wave-uniform
        float vx, vy;
        if (FROMX) {
            float2 v = *(const float2*)(X + (size_t)src * 128 + lane * 2);
            vx = v.x; vy = v.y;
        } else {
            u32 h = *(const u32*)(Hhi + (size_t)src * 512 + lane * 2);
            u32 l = *(const u32*)(Hlo + (size_t)src * 512 + lane * 2);
            vx = bf2f((u16)h) + bf2f((u16)l);
            vy = bf2f((u16)(h >> 16)) + bf2f((u16)(l >> 16));
        }
        if (t == 0)      { a0x += vx; a0y += vy; }
        else if (t == 1) { a1x += vx; a1y += vy; }
        else             { a2x += vx; a2y += vy; }
    }
    float s0 = 1.f / fmaxf((float)cnt[node], 1.f);
    float s1 = 1.f / fmaxf((float)cnt[NN + node], 1.f);
    float s2 = 1.f / fmaxf((float)cnt[2 * NN + node], 1.f);
    a0x *= s0; a0y *= s0; a1x *= s1; a1y *= s1; a2x *= s2; a2y *= s2;
    size_t base = (size_t)node * 512 + 128 + lane * 2;
    auto wrpair = [&](float vx, float vy, size_t off) {
        u16 hx = f2bf(vx), hy = f2bf(vy);
        u16 lx = f2bf(vx - bf2f(hx)), ly = f2bf(vy - bf2f(hy));
        *(u32*)(Shi + off) = (u32)hx | ((u32)hy << 16);
        *(u32*)(Slo + off) = (u32)lx | ((u32)ly << 16);
    };
    wrpair(a0x, a0y, base);
    wrpair(a1x, a1y, base + 128);
    wrpair(a2x, a2y, base + 256);
}

// ---------------------------------------------------------------------------
// bf16x3 MFMA GEMM: C[NN,BN] = A[NN,512] @ W[512,BN] + bias
//   C ~= Ah·Wh + Al·Wh + Ah·Wl  (fp32 accum, rel err ~2^-16)
// 128-row x BN tile, BK=64, 4 waves (2x2), 16x16x32 bf16 MFMA.
// LDS linear (global_load_lds), bank-swizzle applied via source granule XOR.
// PLANES: write h as hi/lo into Out planes cols 0..127; else fp32 OutF [NN,64].
// ---------------------------------------------------------------------------
template<int BN, bool RELU, bool PLANES>
__global__ __launch_bounds__(256)
void mgemm_kernel(const u16* Ahi, const u16* Alo,
                  const u16* Wh, const u16* Wl,
                  const float* bias,
                  u16* OutHi, u16* OutLo, float* OutF)
{
    constexpr int TN  = BN / 32;        // frag-cols per wave (4 or 2)
    constexpr int WC  = BN / 2;         // wave tile col width
    constexpr int NWC = BN / 8;         // W chunks per plane per k-step
    extern __shared__ u16 lds[];
    constexpr int AsH = 0, AsL = 128 * 64, WsH = 2 * 128 * 64, WsL = WsH + BN * 64;

    const int tid  = threadIdx.x;
    const int w    = tid >> 6, lane = tid & 63;
    const int wy   = w >> 1,   wx   = w & 1;
    const int lr   = lane & 15, lg  = lane >> 4;
    const int row0 = blockIdx.x * 128;
    const int sr   = lane >> 3;   // staging: row within chunk
    const int sq   = lane & 7;    // staging: granule index

    f32x4 acc[4][TN];
#pragma unroll
    for (int i = 0; i < 4; i++)
#pragma unroll
        for (int j = 0; j < TN; j++) acc[i][j] = f32x4{0.f, 0.f, 0.f, 0.f};

    for (int k0 = 0; k0 < 512; k0 += 64) {
        __syncthreads();
        // ---- stage A hi/lo: 16 chunks x 1KB per plane (8 rows x 128B) ----
        for (int c = w; c < 16; c += 4) {
            int r  = c * 8 + sr;
            int rr = row0 + r; if (rr >= NN) rr = NN - 1;
            int sg = sq ^ (r & 7);                        // source-granule swizzle
            size_t so = (size_t)rr * 512 + k0 + sg * 8;
            GL2LDS(Ahi + so, &lds[AsH + c * 512 + lane * 8]);
            GL2LDS(Alo + so, &lds[AsL + c * 512 + lane * 8]);
        }
        // ---- stage W hi/lo (transposed layout [BN][512]) ----
        for (int c = w; c < NWC; c += 4) {
            int r  = c * 8 + sr;
            int sg = sq ^ (r & 7);
            size_t so = (size_t)r * 512 + k0 + sg * 8;
            GL2LDS(Wh + so, &lds[WsH + c * 512 + lane * 8]);
            GL2LDS(Wl + so, &lds[WsL + c * 512 + lane * 8]);
        }
        __syncthreads();   // drains vmcnt+lgkmcnt
        // ---- compute: 2 k-chunks of 32 ----
#pragma unroll
        for (int kk = 0; kk < 2; kk++) {
            const int g = kk * 4 + lg;
            short8 aH[4], aL[4];
#pragma unroll
            for (int i = 0; i < 4; i++) {
                int row  = wy * 64 + i * 16 + lr;
                int slot = g ^ (row & 7);
                aH[i] = *(const short8*)&lds[AsH + row * 64 + slot * 8];
                aL[i] = *(const short8*)&lds[AsL + row * 64 + slot * 8];
            }
#pragma unroll
            for (int j = 0; j < TN; j++) {
                int col  = wx * WC + j * 16 + lr;
                int slot = g ^ (col & 7);
                short8 bH = *(const short8*)&lds[WsH + col * 64 + slot * 8];
                short8 bL = *(const short8*)&lds[WsL + col * 64 + slot * 8];
#pragma unroll
                for (int i = 0; i < 4; i++) {
                    acc[i][j] = __builtin_amdgcn_mfma_f32_16x16x32_bf16(aH[i], bH, acc[i][j], 0, 0, 0);
                    acc[i][j] = __builtin_amdgcn_mfma_f32_16x16x32_bf16(aL[i], bH, acc[i][j], 0, 0, 0);
                    acc[i][j] = __builtin_amdgcn_mfma_f32_16x16x32_bf16(aH[i], bL, acc[i][j], 0, 0, 0);
                }
            }
        }
    }
    // ---- epilogue: C/D layout col=lane&15, row=(lane>>4)*4+t ----
#pragma unroll
    for (int i = 0; i < 4; i++) {
#pragma unroll
        for (int t = 0; t < 4; t++) {
            int grow = row0 + wy * 64 + i * 16 + lg * 4 + t;
            if (grow < NN) {
#pragma unroll
                for (int j = 0; j < TN; j++) {
                    int gcol = wx * WC + j * 16 + lr;
                    float v = acc[i][j][t] + bias[gcol];
                    if (RELU) v = fmaxf(v, 0.f);
                    if (PLANES) {
                        u16 hi = f2bf(v);
                        u16 lo = f2bf(v - bf2f(hi));
                        OutHi[(size_t)grow * 512 + gcol] = hi;
                        OutLo[(size_t)grow * 512 + gcol] = lo;
                    } else {
                        OutF[(size_t)grow * 64 + gcol] = v;
                    }
                }
            }
        }
    }
}

// ---------------------------------------------------------------------------
// Final pair MLP
// ---------------------------------------------------------------------------
__global__ __launch_bounds__(128)
void fc_kernel(const float* __restrict__ emb, const int* __restrict__ nest,
               const int* __restrict__ food, const float* __restrict__ fw,
               const float* __restrict__ fb, float* __restrict__ out)
{
    __shared__ float pr[128];
    int p = blockIdx.x, j = threadIdx.x;
    int n0 = nest[p], n1 = food[p];
    pr[j] = (j < 64) ? emb[(size_t)n0 * 64 + j] : emb[(size_t)n1 * 64 + (j - 64)];
    __syncthreads();
    float acc = fb[j];
#pragma unroll 8
    for (int k = 0; k < 128; k++) acc = fmaf(pr[k], fw[k * 128 + j], acc);
    out[(size_t)p * 128 + j] = tanhf(acc);
}

// ---------------------------------------------------------------------------
extern "C" void kernel_launch(void* const* d_in, const int* in_sizes, int n_in,
                              void* d_out, int out_size, void* d_ws, size_t ws_size,
                              hipStream_t stream)
{
    const float* x      = (const float*)d_in[0];
    const int*   ei     = (const int*)d_in[1];
    // d_in[2] = edge_attr : dead code in reference
    const int*   et     = (const int*)d_in[3];
    const int*   nest   = (const int*)d_in[4];
    const int*   food   = (const int*)d_in[5];
    const float* basis1 = (const float*)d_in[6];
    const float* comp1  = (const float*)d_in[7];
    const float* root1  = (const float*)d_in[8];
    const float* bias1  = (const float*)d_in[9];
    const float* basis2 = (const float*)d_in[10];
    const float* comp2  = (const float*)d_in[11];
    const float* root2  = (const float*)d_in[12];
    const float* bias2  = (const float*)d_in[13];
    const float* fw     = (const float*)d_in[14];
    const float* fb     = (const float*)d_in[15];

    char* ws = (char*)d_ws;
    size_t off = 0;
    auto take = [&](size_t bytes) -> char* {
        char* p = ws + off;
        off += (bytes + 255) & ~(size_t)255;
        return p;
    };
    int*      deg    = (int*)take((size_t)NN * 4);
    int*      cursor = (int*)take((size_t)NN * 4);
    int*      cnt    = (int*)take((size_t)3 * NN * 4);
    size_t    zero_bytes = (size_t)((char*)(cnt + 3 * NN) - (char*)deg);
    int*      offs   = (int*)take((size_t)(NN + 1) * 4);
    unsigned* ep     = (unsigned*)take((size_t)NE * 4);
    u16*      W1h    = (u16*)take((size_t)128 * 512 * 2);
    u16*      W1l    = (u16*)take((size_t)128 * 512 * 2);
    u16*      W2h    = (u16*)take((size_t)64 * 512 * 2);
    u16*      W2l    = (u16*)take((size_t)64 * 512 * 2);
    u16*      Ahi    = (u16*)take((size_t)NN * 512 * 2);
    u16*      Alo    = (u16*)take((size_t)NN * 512 * 2);
    float*    emb    = (float*)take((size_t)NN * 64 * 4);

    hipMemsetAsync(deg, 0, zero_bytes, stream);

    build_w_kernel<<<384, 256, 0, stream>>>(basis1, comp1, root1, basis2, comp2, root2,
                                            W1h, W1l, W2h, W2l);
    convert_x_kernel<<<(NN * 64 + 255) / 256, 256, 0, stream>>>(x, Ahi, Alo);
    hist_kernel<<<1024, 256, 0, stream>>>(ei, et, deg, cnt);
    scan_kernel<<<1, 1024, 0, stream>>>(deg, offs);
    scatter_kernel<<<1024, 256, 0, stream>>>(ei, et, offs, cursor, ep);

    // Layer 1: aggregate raw x -> A plane cols 128.., then MFMA GEMM -> h (cols 0..127)
    agg_kernel<true><<<(NN * 64 + 255) / 256, 256, 0, stream>>>(x, nullptr, nullptr, ep, offs, cnt, Ahi, Alo);
    mgemm_kernel<128, true, true><<<(NN + 127) / 128, 256, (2*128*64 + 2*128*64) * 2, stream>>>(
        Ahi, Alo, W1h, W1l, bias1, Ahi, Alo, nullptr);

    // Layer 2: aggregate h (planes cols 0..127) -> cols 128.., GEMM -> emb fp32
    agg_kernel<false><<<(NN * 64 + 255) / 256, 256, 0, stream>>>(nullptr, Ahi, Alo, ep, offs, cnt, Ahi, Alo);
    mgemm_kernel<64, false, false><<<(NN + 127) / 128, 256, (2*128*64 + 2*64*64) * 2, stream>>>(
        Ahi, Alo, W2h, W2l, bias2, nullptr, nullptr, emb);

    fc_kernel<<<NB, 128, 0, stream>>>(emb, nest, food, fw, fb, (float*)d_out);
}